// Round 21
// baseline (546.747 us; speedup 1.0000x reference)
//
#include <hip/hip_runtime.h>
#include <math.h>

#define LOG2E 1.4426950408889634f

#if __has_builtin(__builtin_amdgcn_exp2f)
#define EXP2(x) __builtin_amdgcn_exp2f(x)
#else
#define EXP2(x) exp2f(x)
#endif

constexpr int B_ = 4, N_ = 2048, H_ = 4, D_ = 32, HD_ = 128;
constexpr int BH_ = B_ * H_;          // 16
constexpr int ROWS_ = BH_ * N_;       // 32768
constexpr size_t M_ = (size_t)ROWS_ * D_;  // 1,048,576 floats

typedef float v4f __attribute__((ext_vector_type(4)));
typedef _Float16 h2 __attribute__((ext_vector_type(2)));

// x[BN,K] @ Wl/Wr[K,128] + bl/br ->
//   xl   f32 [bh][n][d]   (k_u only)
//   xlh  f16 [bh][n][d]   (score + PV source rows)
//   xrh  f16 [bh][n][d]   (per-lane target rows)
__global__ __launch_bounds__(256) void k_linear(
    const float* __restrict__ x,
    const float* __restrict__ Wl, const float* __restrict__ bl,
    const float* __restrict__ Wr, const float* __restrict__ br,
    float* __restrict__ xl, unsigned short* __restrict__ xlh,
    unsigned short* __restrict__ xrh, int K)
{
    __shared__ __align__(16) float xs[32 * 128];
    const int tid = threadIdx.x;
    const int r0 = blockIdx.x * 32;
    const float4* src = (const float4*)(x + (size_t)r0 * K);
    float4* dst = (float4*)xs;
    for (int idx = tid; idx < 8 * K; idx += 256) dst[idx] = src[idx];
    __syncthreads();

    const int c  = tid & 127;
    const int rg = tid >> 7;
    float accl[16], accr[16];
    const float blv = bl[c], brv = br[c];
    #pragma unroll
    for (int r = 0; r < 16; r++) { accl[r] = blv; accr[r] = brv; }
    #pragma unroll 8
    for (int k = 0; k < K; k++) {
        const float wl = Wl[k * HD_ + c];
        const float wr = Wr[k * HD_ + c];
        #pragma unroll
        for (int r = 0; r < 16; r++) {
            const float xv = xs[(rg * 16 + r) * K + k];
            accl[r] = fmaf(xv, wl, accl[r]);
            accr[r] = fmaf(xv, wr, accr[r]);
        }
    }
    const int h = c >> 5, d = c & 31;
    #pragma unroll
    for (int r = 0; r < 16; r++) {
        const int row = r0 + rg * 16 + r;
        const int b = row >> 11, n = row & (N_ - 1);
        const size_t o = (((size_t)(b * H_ + h)) * N_ + n) * D_ + d;
        xl[o] = accl[r];
        xlh[o] = __builtin_bit_cast(unsigned short, (_Float16)accl[r]);
        xrh[o] = __builtin_bit_cast(unsigned short, (_Float16)accr[r]);
    }
}

// u_j = 0.6*log2e * att_h . xl_j  (target-side term cancels in softmax)
__global__ __launch_bounds__(256) void k_u(
    const float* __restrict__ xl, const float* __restrict__ att,
    float* __restrict__ u)
{
    const int idx = blockIdx.x * 256 + threadIdx.x; // [0, ROWS_)
    const int h = (idx / N_) & (H_ - 1);
    const float4* a4 = (const float4*)(att + h * D_);
    const float4* l4 = (const float4*)(xl + (size_t)idx * D_);
    float su = 0.f;
    #pragma unroll
    for (int q = 0; q < 8; q++) {
        const float4 a = a4[q], lv = l4[q];
        su += a.x * lv.x + a.y * lv.y + a.z * lv.z + a.w * lv.w;
    }
    u[idx] = 0.6f * LOG2E * su;
}

// Per-row sound upper bound on e (log2 domain); also packs tch.
// EXACT R15/R19 version (passed at absmax 0.0156) - no numeric changes.
__global__ __launch_bounds__(512) void k_bound(
    const unsigned int* __restrict__ xlh, const unsigned int* __restrict__ xrh,
    const float* __restrict__ u, const float* __restrict__ att,
    float* __restrict__ bound, unsigned int* __restrict__ tch)
{
    __shared__ float redA[16][33];
    __shared__ float redB[16][33];
    __shared__ float clv[32];
    __shared__ float tca[32];
    __shared__ float redu[512];
    const int bh = blockIdx.x, h = bh & (H_ - 1), t = threadIdx.x;

    if (bh < H_ && t < 16) {
        h2 v;
        v.x = (_Float16)(att[bh * D_ + 2 * t]     * (0.4f * LOG2E));
        v.y = (_Float16)(att[bh * D_ + 2 * t + 1] * (0.4f * LOG2E));
        tch[bh * 16 + t] = __builtin_bit_cast(unsigned int, v);
    }
    if (t < 16) {
        _Float16 a = (_Float16)(att[h * D_ + 2 * t]     * (0.4f * LOG2E));
        _Float16 b = (_Float16)(att[h * D_ + 2 * t + 1] * (0.4f * LOG2E));
        tca[2 * t]     = fabsf((float)a);
        tca[2 * t + 1] = fabsf((float)b);
    }
    const unsigned int* xb = xlh + (size_t)bh * N_ * 16;
    const int p = t & 15, rg = t >> 4;
    float m0 = 0.f, m1 = 0.f;
    for (int r = rg; r < N_; r += 32) {
        h2 z = __builtin_bit_cast(h2, xb[r * 16 + p] & 0x7FFF7FFFu);
        m0 = fmaxf(m0, (float)z.x);
        m1 = fmaxf(m1, (float)z.y);
    }
    redA[p][rg] = m0; redB[p][rg] = m1;
    const float* ub = u + (size_t)bh * N_;
    float um = -1e30f;
    for (int r = t; r < N_; r += 512) um = fmaxf(um, ub[r]);
    redu[t] = um;
    __syncthreads();
    if (t < 16) {
        float a = 0.f, b = 0.f;
        for (int g = 0; g < 32; g++) { a = fmaxf(a, redA[t][g]); b = fmaxf(b, redB[t][g]); }
        clv[2 * t] = a; clv[2 * t + 1] = b;
    }
    for (int s = 256; s > 0; s >>= 1) {
        if (t < s) redu[t] = fmaxf(redu[t], redu[t + s]);
        __syncthreads();
    }
    const float umax = redu[0];
    const unsigned int* xrb = xrh + (size_t)bh * N_ * 16;
    for (int r = t; r < N_; r += 512) {
        float s = 0.f;
        #pragma unroll
        for (int k = 0; k < 16; k++) {
            h2 z = __builtin_bit_cast(h2, xrb[r * 16 + k] & 0x7FFF7FFFu);
            s += tca[2 * k] * (clv[2 * k] + (float)z.x)
               + tca[2 * k + 1] * (clv[2 * k + 1] + (float)z.y);
        }
        bound[bh * N_ + r] = umax + s + 0.25f;
    }
}

// v_dot2_f32_f16 is ~quarter-rate on gfx950 (the 160-200us plateau across
// R12/R15/R19; busy-cycle fits within 8%). Full-rate replacement:
// pk_add_f16 + v_and (packed abs) + v_fma_mix_f32 (f32 accumulate, 2cyc).
// R20 LESSON: op_sel half-select on an SGPR src0 corrupted the hi-half
// coefficients (absmax 12.9). Fix: score coefficients pre-converted to
// f32 in VGPRs (tf[32]); op_sel now appears ONLY on VGPR src1 (z / S) --
// the standard mix-op pattern. PV uses the same f32 p for l and o.

// score group K (dim-pair K): z=|S_K+xr_K| (f16x2);
// EA += tf[2K]*z.lo ; EB += tf[2K+1]*z.hi   (f32 coeff, f16 z-half, f32 acc)
#define SG(K, EA, EB)                                                          \
    "v_pk_add_f16 %[z], %[s" K "], %[x" K "]\n\t"                              \
    "v_and_b32 %[z], %[mk], %[z]\n\t"                                          \
    "v_fma_mix_f32 %[" EA "], %[tl" K "], %[z], %[" EA "] op_sel:[0,0,0] op_sel_hi:[0,1,0]\n\t" \
    "v_fma_mix_f32 %[" EB "], %[th" K "], %[z], %[" EB "] op_sel:[0,1,0] op_sel_hi:[0,1,0]\n\t"

// PV group: o[2k] += p * S_k.lo ; o[2k+1] += p * S_k.hi  (p f32, S f16)
#define PVG(KL, KH, SK)                                                        \
    "v_fma_mix_f32 %[o" KL "], %[p], %[s" SK "], %[o" KL "] op_sel:[0,0,0] op_sel_hi:[0,1,0]\n\t" \
    "v_fma_mix_f32 %[o" KH "], %[p], %[s" SK "], %[o" KH "] op_sel:[0,1,0] op_sel_hi:[0,1,0]\n\t"

__global__ __launch_bounds__(256) void k_attn(
    const unsigned int* __restrict__ xlh,   // [bh][n][16] u32 (d-pairs)
    const unsigned int* __restrict__ xrh,
    const float* __restrict__ u, const float* __restrict__ bound,
    const unsigned int* __restrict__ tch,
    float* __restrict__ P, float* __restrict__ lb, int jlen)
{
    __shared__ __align__(16) uint4 s_xlh[1024];   // 256 j-rows x 4 uint4 (16KB)
    __shared__ float s_u[256];
    __shared__ float s_pad[4096];                 // 16KB pad: pins 4 blocks/CU
    const int tid = threadIdx.x;
    const int t128 = blockIdx.x & 127, part = blockIdx.x >> 7;
    const int bh = t128 >> 3;
    const int h  = bh & (H_ - 1);
    const int row = bh * N_ + (t128 & 7) * 256 + tid;
    if (jlen < 0) s_pad[tid] = 0.f;               // keep pad allocated

    // f32 score coefficients in VGPRs (no op_sel / no SGPR-half hazards)
    float tf[32];
    #pragma unroll
    for (int k = 0; k < 16; k++) {
        const h2 t2 = __builtin_bit_cast(h2, tch[h * 16 + k]);
        tf[2 * k]     = (float)t2.x;
        tf[2 * k + 1] = (float)t2.y;
    }

    unsigned int xrp[16];
    {
        const uint4* s = (const uint4*)(xrh + (size_t)row * 16);
        const uint4 a = s[0], b = s[1], c = s[2], d = s[3];
        xrp[0]=a.x; xrp[1]=a.y; xrp[2]=a.z; xrp[3]=a.w;
        xrp[4]=b.x; xrp[5]=b.y; xrp[6]=b.z; xrp[7]=b.w;
        xrp[8]=c.x; xrp[9]=c.y; xrp[10]=c.z; xrp[11]=c.w;
        xrp[12]=d.x; xrp[13]=d.y; xrp[14]=d.z; xrp[15]=d.w;
    }
    const float negb = -bound[row];
    const unsigned int kAbsMask = 0x7FFF7FFFu;

    float l = 0.f;
    float o[32];
    #pragma unroll
    for (int k = 0; k < 32; k++) o[k] = 0.f;

    const uint4* gx = (const uint4*)(xlh + (size_t)bh * N_ * 16);
    const float* u_b = u + (size_t)bh * N_;

    const int jbeg = part * jlen;
    for (int jt = 0; jt < jlen; jt += 256) {
        if (jt) __syncthreads();
        const int j0 = jbeg + jt;
        #pragma unroll
        for (int k = 0; k < 4; k++)
            s_xlh[tid + 256 * k] = gx[(size_t)j0 * 4 + tid + 256 * k];
        s_u[tid] = u_b[j0 + tid];
        __syncthreads();

        for (int j = 0; j < 256; j++) {
            const uint4 S0 = s_xlh[4 * j + 0], S1 = s_xlh[4 * j + 1];
            const uint4 S2 = s_xlh[4 * j + 2], S3 = s_xlh[4 * j + 3];
            float e0 = s_u[j] + negb, e1 = 0.f, e2 = 0.f, e3 = 0.f;
            unsigned int zz;
            asm(SG("0",  "e0", "e1") SG("1",  "e2", "e3")
                SG("2",  "e0", "e1") SG("3",  "e2", "e3")
                SG("4",  "e0", "e1") SG("5",  "e2", "e3")
                SG("6",  "e0", "e1") SG("7",  "e2", "e3")
                SG("8",  "e0", "e1") SG("9",  "e2", "e3")
                SG("10", "e0", "e1") SG("11", "e2", "e3")
                SG("12", "e0", "e1") SG("13", "e2", "e3")
                SG("14", "e0", "e1") SG("15", "e2", "e3")
                : [e0]"+v"(e0), [e1]"+v"(e1), [e2]"+v"(e2), [e3]"+v"(e3),
                  [z]"=&v"(zz)
                : [s0]"v"(S0.x),  [s1]"v"(S0.y),  [s2]"v"(S0.z),  [s3]"v"(S0.w),
                  [s4]"v"(S1.x),  [s5]"v"(S1.y),  [s6]"v"(S1.z),  [s7]"v"(S1.w),
                  [s8]"v"(S2.x),  [s9]"v"(S2.y),  [s10]"v"(S2.z), [s11]"v"(S2.w),
                  [s12]"v"(S3.x), [s13]"v"(S3.y), [s14]"v"(S3.z), [s15]"v"(S3.w),
                  [x0]"v"(xrp[0]),   [x1]"v"(xrp[1]),   [x2]"v"(xrp[2]),   [x3]"v"(xrp[3]),
                  [x4]"v"(xrp[4]),   [x5]"v"(xrp[5]),   [x6]"v"(xrp[6]),   [x7]"v"(xrp[7]),
                  [x8]"v"(xrp[8]),   [x9]"v"(xrp[9]),   [x10]"v"(xrp[10]), [x11]"v"(xrp[11]),
                  [x12]"v"(xrp[12]), [x13]"v"(xrp[13]), [x14]"v"(xrp[14]), [x15]"v"(xrp[15]),
                  [tl0]"v"(tf[0]),   [th0]"v"(tf[1]),   [tl1]"v"(tf[2]),   [th1]"v"(tf[3]),
                  [tl2]"v"(tf[4]),   [th2]"v"(tf[5]),   [tl3]"v"(tf[6]),   [th3]"v"(tf[7]),
                  [tl4]"v"(tf[8]),   [th4]"v"(tf[9]),   [tl5]"v"(tf[10]),  [th5]"v"(tf[11]),
                  [tl6]"v"(tf[12]),  [th6]"v"(tf[13]),  [tl7]"v"(tf[14]),  [th7]"v"(tf[15]),
                  [tl8]"v"(tf[16]),  [th8]"v"(tf[17]),  [tl9]"v"(tf[18]),  [th9]"v"(tf[19]),
                  [tl10]"v"(tf[20]), [th10]"v"(tf[21]), [tl11]"v"(tf[22]), [th11]"v"(tf[23]),
                  [tl12]"v"(tf[24]), [th12]"v"(tf[25]), [tl13]"v"(tf[26]), [th13]"v"(tf[27]),
                  [tl14]"v"(tf[28]), [th14]"v"(tf[29]), [tl15]"v"(tf[30]), [th15]"v"(tf[31]),
                  [mk]"s"(kAbsMask));
            const float p = EXP2((e0 + e1) + (e2 + e3));
            l += p;
            asm(PVG("0",  "1",  "0")  PVG("2",  "3",  "1")
                PVG("4",  "5",  "2")  PVG("6",  "7",  "3")
                PVG("8",  "9",  "4")  PVG("10", "11", "5")
                PVG("12", "13", "6")  PVG("14", "15", "7")
                PVG("16", "17", "8")  PVG("18", "19", "9")
                PVG("20", "21", "10") PVG("22", "23", "11")
                PVG("24", "25", "12") PVG("26", "27", "13")
                PVG("28", "29", "14") PVG("30", "31", "15")
                : [o0]"+v"(o[0]),   [o1]"+v"(o[1]),   [o2]"+v"(o[2]),   [o3]"+v"(o[3]),
                  [o4]"+v"(o[4]),   [o5]"+v"(o[5]),   [o6]"+v"(o[6]),   [o7]"+v"(o[7]),
                  [o8]"+v"(o[8]),   [o9]"+v"(o[9]),   [o10]"+v"(o[10]), [o11]"+v"(o[11]),
                  [o12]"+v"(o[12]), [o13]"+v"(o[13]), [o14]"+v"(o[14]), [o15]"+v"(o[15]),
                  [o16]"+v"(o[16]), [o17]"+v"(o[17]), [o18]"+v"(o[18]), [o19]"+v"(o[19]),
                  [o20]"+v"(o[20]), [o21]"+v"(o[21]), [o22]"+v"(o[22]), [o23]"+v"(o[23]),
                  [o24]"+v"(o[24]), [o25]"+v"(o[25]), [o26]"+v"(o[26]), [o27]"+v"(o[27]),
                  [o28]"+v"(o[28]), [o29]"+v"(o[29]), [o30]"+v"(o[30]), [o31]"+v"(o[31])
                : [p]"v"(p),
                  [s0]"v"(S0.x),  [s1]"v"(S0.y),  [s2]"v"(S0.z),  [s3]"v"(S0.w),
                  [s4]"v"(S1.x),  [s5]"v"(S1.y),  [s6]"v"(S1.z),  [s7]"v"(S1.w),
                  [s8]"v"(S2.x),  [s9]"v"(S2.y),  [s10]"v"(S2.z), [s11]"v"(S2.w),
                  [s12]"v"(S3.x), [s13]"v"(S3.y), [s14]"v"(S3.z), [s15]"v"(S3.w));
        }
    }

    float* Pp = P + (size_t)part * M_ + (size_t)row * D_;
    #pragma unroll
    for (int k = 0; k < 8; k++) {
        v4f w;
        w.x = o[4*k]; w.y = o[4*k+1]; w.z = o[4*k+2]; w.w = o[4*k+3];
        ((v4f*)Pp)[k] = w;
    }
    lb[part * ROWS_ + row] = l;
}

// Fused: merge JS partials (shared bound -> sum(o)/sum(l)) + bias + LN(128)
// (+optional ReLU). One 64-thread block per node row (b,n).
template <int JS>
__global__ __launch_bounds__(64) void k_comb_ln(
    const float* __restrict__ P, const float* __restrict__ lb,
    const float* __restrict__ bias, const float* __restrict__ g,
    const float* __restrict__ bta, float* __restrict__ outp, int do_relu)
{
    const int row = blockIdx.x;                    // b*N+n
    const int b = row >> 11, n = row & (N_ - 1);
    const int t = threadIdx.x;
    const int c0 = t, c1 = t + 64;
    const int bh0 = b * H_ + (c0 >> 5), bh1 = b * H_ + (c1 >> 5);
    const size_t i0 = ((size_t)bh0 * N_ + n) * D_ + (c0 & 31);
    const size_t i1 = ((size_t)bh1 * N_ + n) * D_ + (c1 & 31);
    float a0 = 0.f, a1 = 0.f, L0 = 0.f, L1 = 0.f;
    #pragma unroll
    for (int s = 0; s < JS; s++) {
        a0 += P[(size_t)s * M_ + i0];
        a1 += P[(size_t)s * M_ + i1];
        L0 += lb[s * ROWS_ + bh0 * N_ + n];
        L1 += lb[s * ROWS_ + bh1 * N_ + n];
    }
    const float x0 = a0 / L0 + bias[c0];
    const float x1 = a1 / L1 + bias[c1];
    float s = x0 + x1;
    #pragma unroll
    for (int w = 1; w < 64; w <<= 1) s += __shfl_xor(s, w);
    const float mu = s * (1.f / 128.f);
    const float d0 = x0 - mu, d1 = x1 - mu;
    float q = d0 * d0 + d1 * d1;
    #pragma unroll
    for (int w = 1; w < 64; w <<= 1) q += __shfl_xor(q, w);
    const float rstd = rsqrtf(q * (1.f / 128.f) + 1e-5f);
    float y0 = d0 * rstd * g[c0] + bta[c0];
    float y1 = d1 * rstd * g[c1] + bta[c1];
    if (do_relu) { y0 = fmaxf(y0, 0.f); y1 = fmaxf(y1, 0.f); }
    outp[(size_t)row * HD_ + c0] = y0;
    outp[(size_t)row * HD_ + c1] = y1;
}

extern "C" void kernel_launch(void* const* d_in, const int* in_sizes, int n_in,
                              void* d_out, int out_size, void* d_ws, size_t ws_size,
                              hipStream_t stream) {
    const float* x    = (const float*)d_in[0];
    const float* Wl1  = (const float*)d_in[2];
    const float* bl1  = (const float*)d_in[3];
    const float* Wr1  = (const float*)d_in[4];
    const float* br1  = (const float*)d_in[5];
    const float* att1 = (const float*)d_in[6];
    const float* bias1= (const float*)d_in[7];
    const float* ln1g = (const float*)d_in[8];
    const float* ln1b = (const float*)d_in[9];
    const float* Wl2  = (const float*)d_in[10];
    const float* bl2  = (const float*)d_in[11];
    const float* Wr2  = (const float*)d_in[12];
    const float* br2  = (const float*)d_in[13];
    const float* att2 = (const float*)d_in[14];
    const float* bias2= (const float*)d_in[15];
    const float* ln2g = (const float*)d_in[16];
    const float* ln2b = (const float*)d_in[17];

    float* ws = (float*)d_ws;
    float* xl = ws;                                   // M_
    unsigned short* xlh = (unsigned short*)(xl + M_); // M_ halfs
    unsigned short* xrh = xlh + M_;                   // M_ halfs
    float* u     = xl + 2 * M_;                       // ROWS_
    float* bound = u + ROWS_;                         // ROWS_
    unsigned int* tch = (unsigned int*)(bound + ROWS_); // 64 u32

    // j-split: largest fitting. floats = 2M + 2R + 64 + js*(M+R) + M (h slab)
    int js = 1;
    for (int cand = 8; cand >= 1; cand >>= 1) {
        const size_t need = ((size_t)3 * M_ + 2 * ROWS_ + 64
                             + (size_t)cand * (M_ + ROWS_)) * sizeof(float);
        if (ws_size >= need) { js = cand; break; }
    }
    const int jlen = N_ / js;

    float* P  = (float*)(tch + 64);        // js * M_
    float* lb = P + (size_t)js * M_;       // js * ROWS_
    float* h  = lb + (size_t)js * ROWS_;   // M_ (dedicated slab)
    float* outf = (float*)d_out;

    const int BN = B_ * N_;                // 8192
    // ---- layer 1 ----
    k_linear<<<BN / 32, 256, 0, stream>>>(x, Wl1, bl1, Wr1, br1, xl, xlh, xrh, 32);
    k_u<<<ROWS_ / 256, 256, 0, stream>>>(xl, att1, u);
    k_bound<<<BH_, 512, 0, stream>>>((const unsigned int*)xlh, (const unsigned int*)xrh,
                                     u, att1, bound, tch);
    k_attn<<<128 * js, 256, 0, stream>>>((const unsigned int*)xlh,
                                         (const unsigned int*)xrh, u, bound, tch, P, lb, jlen);
    if      (js == 8) k_comb_ln<8><<<BN, 64, 0, stream>>>(P, lb, bias1, ln1g, ln1b, h, 1);
    else if (js == 4) k_comb_ln<4><<<BN, 64, 0, stream>>>(P, lb, bias1, ln1g, ln1b, h, 1);
    else if (js == 2) k_comb_ln<2><<<BN, 64, 0, stream>>>(P, lb, bias1, ln1g, ln1b, h, 1);
    else              k_comb_ln<1><<<BN, 64, 0, stream>>>(P, lb, bias1, ln1g, ln1b, h, 1);
    // ---- layer 2 ----
    k_linear<<<BN / 32, 256, 0, stream>>>(h, Wl2, bl2, Wr2, br2, xl, xlh, xrh, 128);
    k_u<<<ROWS_ / 256, 256, 0, stream>>>(xl, att2, u);
    k_bound<<<BH_, 512, 0, stream>>>((const unsigned int*)xlh, (const unsigned int*)xrh,
                                     u, att2, bound, tch);
    k_attn<<<128 * js, 256, 0, stream>>>((const unsigned int*)xlh,
                                         (const unsigned int*)xrh, u, bound, tch, P, lb, jlen);
    if      (js == 8) k_comb_ln<8><<<BN, 64, 0, stream>>>(P, lb, bias2, ln2g, ln2b, outf, 0);
    else if (js == 4) k_comb_ln<4><<<BN, 64, 0, stream>>>(P, lb, bias2, ln2g, ln2b, outf, 0);
    else if (js == 2) k_comb_ln<2><<<BN, 64, 0, stream>>>(P, lb, bias2, ln2g, ln2b, outf, 0);
    else              k_comb_ln<1><<<BN, 64, 0, stream>>>(P, lb, bias2, ln2g, ln2b, outf, 0);
}